// Round 1
// baseline (89.010 us; speedup 1.0000x reference)
//
#include <hip/hip_runtime.h>
#include <math.h>

#define N_ROWS 8192
#define HDIM   1024
#define KK     10
#define EPSF   1e-8f

// Main kernel: one wave per row (grid-stride). Centers register-resident
// (160 VGPRs) to keep the LDS pipe idle — LDS-staged centers would cost
// ~15k LDS cycles/CU vs ~13k memory cycles (would flip the bottleneck).
__global__ __launch_bounds__(256, 2)
void knife_main(const float* __restrict__ x,
                const float* __restrict__ centers,
                const float* __restrict__ weights,
                const float* __restrict__ scales,
                float* __restrict__ partials) {
    const int lane = threadIdx.x & 63;
    const int wave_in_block = threadIdx.x >> 6;
    const int gwave = blockIdx.x * 4 + wave_in_block;   // 2048 waves @ grid 512
    const int nwaves = gridDim.x * 4;

    // Preload centers: lane owns float4 positions lane + 64*j, j=0..3
    const float4* c4 = (const float4*)centers;
    float4 c[KK][4];
#pragma unroll
    for (int k = 0; k < KK; ++k) {
#pragma unroll
        for (int j = 0; j < 4; ++j) {
            c[k][j] = c4[k * (HDIM / 4) + lane + 64 * j];
        }
    }

    // ||c_k||^2 once per wave (butterfly broadcast -> uniform in all lanes)
    float csq[KK];
#pragma unroll
    for (int k = 0; k < KK; ++k) {
        float s = 0.f;
#pragma unroll
        for (int j = 0; j < 4; ++j) {
            float4 v = c[k][j];
            s += v.x * v.x + v.y * v.y + v.z * v.z + v.w * v.w;
        }
#pragma unroll
        for (int off = 32; off > 0; off >>= 1) s += __shfl_xor(s, off, 64);
        csq[k] = s;
    }

    // weights/scales: uniform-address loads -> scalar regs
    float w[KK], inv2s2[KK];
#pragma unroll
    for (int k = 0; k < KK; ++k) {
        w[k] = weights[k];
        float sc = scales[k];
        inv2s2[k] = 1.0f / (2.0f * sc * sc);
    }

    float logsum = 0.f;
    for (int row = gwave; row < N_ROWS; row += nwaves) {
        const float4* xr = (const float4*)(x + (size_t)row * HDIM);
        float4 xv[4];
#pragma unroll
        for (int j = 0; j < 4; ++j) xv[j] = xr[lane + 64 * j];

        float acc[KK + 1];
#pragma unroll
        for (int k = 0; k <= KK; ++k) acc[k] = 0.f;
#pragma unroll
        for (int j = 0; j < 4; ++j) {
            float4 v = xv[j];
            acc[KK] += v.x * v.x + v.y * v.y + v.z * v.z + v.w * v.w;
#pragma unroll
            for (int k = 0; k < KK; ++k) {
                float4 cv = c[k][j];
                acc[k] += v.x * cv.x + v.y * cv.y + v.z * cv.z + v.w * cv.w;
            }
        }
        // Butterfly-reduce all 11 accumulators; result broadcast to every lane
#pragma unroll
        for (int k = 0; k <= KK; ++k) {
            float s = acc[k];
#pragma unroll
            for (int off = 32; off > 0; off >>= 1) s += __shfl_xor(s, off, 64);
            acc[k] = s;
        }
        // Density + log computed uniformly (no divergence)
        float density = 0.f;
#pragma unroll
        for (int k = 0; k < KK; ++k) {
            float d = acc[KK] + csq[k] - 2.0f * acc[k];
            d = fmaxf(d, 0.0f);
            density += w[k] * __expf(-d * inv2s2[k]);
        }
        logsum += __logf(density + EPSF);
    }

    // One partial per block: 4 waves -> LDS -> thread 0 writes partials[block]
    __shared__ float red[4];
    if (lane == 0) red[wave_in_block] = logsum;
    __syncthreads();
    if (threadIdx.x == 0) {
        partials[blockIdx.x] = red[0] + red[1] + red[2] + red[3];
    }
}

// Deterministic final reduction of 512 block partials + output assembly.
__global__ __launch_bounds__(256)
void knife_final(const float* __restrict__ partials, float* __restrict__ out) {
    __shared__ float red[4];
    int t = threadIdx.x;
    float s = partials[t] + partials[t + 256];
#pragma unroll
    for (int off = 32; off > 0; off >>= 1) s += __shfl_xor(s, off, 64);
    if ((t & 63) == 0) red[t >> 6] = s;
    __syncthreads();
    if (t == 0) {
        float total = red[0] + red[1] + red[2] + red[3];
        float h = -total / (float)N_ROWS;   // h_entropy
        out[0] = h;           // entropy_loss (BETA=1)
        out[1] = h * h;       // target_entropy_loss (TARGET=0)
        out[2] = h + h * h;   // total_loss
        out[3] = h;           // h_entropy
    }
}

extern "C" void kernel_launch(void* const* d_in, const int* in_sizes, int n_in,
                              void* d_out, int out_size, void* d_ws, size_t ws_size,
                              hipStream_t stream) {
    const float* x       = (const float*)d_in[0];
    const float* centers = (const float*)d_in[1];
    const float* weights = (const float*)d_in[2];
    const float* scales  = (const float*)d_in[3];
    float* out      = (float*)d_out;
    float* partials = (float*)d_ws;   // 512 floats

    knife_main<<<512, 256, 0, stream>>>(x, centers, weights, scales, partials);
    knife_final<<<1, 256, 0, stream>>>(partials, out);
}

// Round 2
// 86.983 us; speedup vs baseline: 1.0233x; 1.0233x over previous
//
#include <hip/hip_runtime.h>
#include <math.h>

#define N_ROWS 8192
#define HDIM   1024
#define KK     10
#define EPSF   1e-8f

// VALU-pipe wave64 all-reduce via DPP (row_shr / row_bcast), replacing the
// 6-deep ds_swizzle butterfly chain (DS pipe was co-dominant with HBM:
// 2112 swizzles/CU x ~5.8cyc ~= 12k cyc vs 13k memory cyc).
// update_dpp(old=0, src, ctrl, row_mask, bank_mask, bound_ctrl=true):
// masked / out-of-row lanes contribute 0 -> safe to always add.
#define DPP_ADD(x, ctrl, rmask, bmask)                                        \
    x += __int_as_float(__builtin_amdgcn_update_dpp(                          \
        0, __float_as_int(x), ctrl, rmask, bmask, true))

__device__ __forceinline__ float wave_allreduce_add(float x) {
    DPP_ADD(x, 0x111, 0xf, 0xf);  // row_shr:1
    DPP_ADD(x, 0x112, 0xf, 0xf);  // row_shr:2
    DPP_ADD(x, 0x114, 0xf, 0xe);  // row_shr:4
    DPP_ADD(x, 0x118, 0xf, 0xc);  // row_shr:8
    DPP_ADD(x, 0x142, 0xa, 0xf);  // row_bcast:15 (rows 1,3)
    DPP_ADD(x, 0x143, 0xc, 0xf);  // row_bcast:31 (rows 2,3)
    // total lives in lane 63; broadcast as wave-uniform (lands in SGPR)
    return __int_as_float(__builtin_amdgcn_readlane(__float_as_int(x), 63));
}

// One wave per row slice, 4 rows per wave (grid-stride with prefetch).
// Centers register-resident: 160 VGPRs; csq/w/inv2s2 become SGPRs
// (wave-uniform), so total VGPR ~210 -> 2 waves/SIMD.
__global__ __launch_bounds__(256, 2)
void knife_main(const float* __restrict__ x,
                const float* __restrict__ centers,
                const float* __restrict__ weights,
                const float* __restrict__ scales,
                float* __restrict__ partials) {
    const int lane = threadIdx.x & 63;
    const int wid  = threadIdx.x >> 6;
    const int gwave  = blockIdx.x * 4 + wid;   // 2048 waves @ grid 512
    const int nwaves = gridDim.x * 4;
    const int ROWS   = N_ROWS / 2048;          // 4 rows per wave

    // Preload centers: lane owns float4 positions lane + 64*j, j=0..3
    const float4* c4 = (const float4*)centers;
    float4 c[KK][4];
#pragma unroll
    for (int k = 0; k < KK; ++k)
#pragma unroll
        for (int j = 0; j < 4; ++j)
            c[k][j] = c4[k * (HDIM / 4) + lane + 64 * j];

    // ||c_k||^2 once per wave (uniform -> SGPR)
    float csq[KK];
#pragma unroll
    for (int k = 0; k < KK; ++k) {
        float s = 0.f;
#pragma unroll
        for (int j = 0; j < 4; ++j) {
            float4 v = c[k][j];
            s += v.x * v.x + v.y * v.y + v.z * v.z + v.w * v.w;
        }
        csq[k] = wave_allreduce_add(s);
    }

    float w[KK], inv2s2[KK];
#pragma unroll
    for (int k = 0; k < KK; ++k) {
        w[k] = weights[k];
        float sc = scales[k];
        inv2s2[k] = 1.0f / (2.0f * sc * sc);
    }

    const float4* x4 = (const float4*)x;
    float logsum = 0.f;

    int row = gwave;
    float4 xv[4], nx[4];
#pragma unroll
    for (int j = 0; j < 4; ++j)
        xv[j] = x4[((size_t)row << 8) + lane + 64 * j];

#pragma unroll
    for (int i = 0; i < 4; ++i) {   // ROWS == 4
        const int nrow = row + nwaves;
        // Prefetch next row BEFORE the dependent FMA/reduce/exp chain so the
        // ~900-cyc HBM latency overlaps current-row compute.
        if (i + 1 < ROWS) {
#pragma unroll
            for (int j = 0; j < 4; ++j)
                nx[j] = x4[((size_t)nrow << 8) + lane + 64 * j];
        }

        float acc[KK + 1];
#pragma unroll
        for (int k = 0; k <= KK; ++k) acc[k] = 0.f;
#pragma unroll
        for (int j = 0; j < 4; ++j) {
            float4 v = xv[j];
            acc[KK] += v.x * v.x + v.y * v.y + v.z * v.z + v.w * v.w;
#pragma unroll
            for (int k = 0; k < KK; ++k) {
                float4 cv = c[k][j];
                acc[k] += v.x * cv.x + v.y * cv.y + v.z * cv.z + v.w * cv.w;
            }
        }

        // 11 independent 6-step DPP chains -> pipeline on VALU
        float xsq = wave_allreduce_add(acc[KK]);
        float density = 0.f;
#pragma unroll
        for (int k = 0; k < KK; ++k) {
            float dot = wave_allreduce_add(acc[k]);
            float d = fmaxf(xsq + csq[k] - 2.0f * dot, 0.0f);
            density += w[k] * __expf(-d * inv2s2[k]);
        }
        logsum += __logf(density + EPSF);

#pragma unroll
        for (int j = 0; j < 4; ++j) xv[j] = nx[j];
        row = nrow;
    }

    __shared__ float red[4];
    if (lane == 0) red[wid] = logsum;
    __syncthreads();
    if (threadIdx.x == 0)
        partials[blockIdx.x] = red[0] + red[1] + red[2] + red[3];
}

// Deterministic final reduction of 512 block partials + output assembly.
__global__ __launch_bounds__(256)
void knife_final(const float* __restrict__ partials, float* __restrict__ out) {
    __shared__ float red[4];
    int t = threadIdx.x;
    float s = partials[t] + partials[t + 256];
    s = wave_allreduce_add(s);
    if ((t & 63) == 0) red[t >> 6] = s;
    __syncthreads();
    if (t == 0) {
        float total = red[0] + red[1] + red[2] + red[3];
        float h = -total / (float)N_ROWS;   // h_entropy
        out[0] = h;           // entropy_loss (BETA=1)
        out[1] = h * h;       // target_entropy_loss (TARGET=0)
        out[2] = h + h * h;   // total_loss
        out[3] = h;           // h_entropy
    }
}

extern "C" void kernel_launch(void* const* d_in, const int* in_sizes, int n_in,
                              void* d_out, int out_size, void* d_ws, size_t ws_size,
                              hipStream_t stream) {
    const float* x       = (const float*)d_in[0];
    const float* centers = (const float*)d_in[1];
    const float* weights = (const float*)d_in[2];
    const float* scales  = (const float*)d_in[3];
    float* out      = (float*)d_out;
    float* partials = (float*)d_ws;   // 512 floats

    knife_main<<<512, 256, 0, stream>>>(x, centers, weights, scales, partials);
    knife_final<<<1, 256, 0, stream>>>(partials, out);
}